// Round 6
// baseline (558.207 us; speedup 1.0000x reference)
//
#include <hip/hip_runtime.h>
#include <hip/hip_bf16.h>
#include <cstdint>

typedef short bf16x8 __attribute__((ext_vector_type(8)));
typedef float f32x4 __attribute__((ext_vector_type(4)));

// ---------------- bf16 helpers ----------------

__device__ inline float blo(uint u) { return __uint_as_float(u << 16); }
__device__ inline float bhi(uint u) { return __uint_as_float(u & 0xffff0000u); }
__device__ inline ushort f2bu(float x) {
    __hip_bfloat16 h = __float2bfloat16(x);
    return *reinterpret_cast<ushort*>(&h);
}
__device__ inline uint fpack2(float x, float y) {
    return (uint)f2bu(x) | ((uint)f2bu(y) << 16);
}

// ================= bucketed CSR build =================

__global__ __launch_bounds__(256) void hist_k(const int* __restrict__ ei,
                                              uint* __restrict__ hist, int E, int n) {
    __shared__ uint h[256];
    int t = threadIdx.x, blk = blockIdx.x;
    int nb = (n + 511) >> 9;
    h[t] = 0;
    __syncthreads();
    int chunk = (E + 255) / 256;
    int e0 = blk * chunk, e1 = min(E, e0 + chunk);
    for (int e = e0 + t; e < e1; e += 256)
        atomicAdd(&h[((uint)ei[(size_t)E + e]) >> 9], 1u);
    __syncthreads();
    if (t < nb) hist[(size_t)t * 256 + blk] = h[t];
}

__global__ __launch_bounds__(256) void scanA_k(const uint* __restrict__ hist,
                                               uint* __restrict__ histex,
                                               uint* __restrict__ btot) {
    __shared__ uint s[256];
    int t = threadIdx.x, b = blockIdx.x;
    uint v = hist[(size_t)b * 256 + t];
    s[t] = v;
    __syncthreads();
    for (int off = 1; off < 256; off <<= 1) {
        uint u = (t >= off) ? s[t - off] : 0;
        __syncthreads();
        s[t] += u;
        __syncthreads();
    }
    histex[(size_t)b * 256 + t] = s[t] - v;
    if (t == 255) btot[b] = s[255];
}

__global__ __launch_bounds__(256) void scanB_k(const uint* __restrict__ btot,
                                               uint* __restrict__ bbase,
                                               int* __restrict__ rp, int n, int E) {
    __shared__ uint s[256];
    int t = threadIdx.x;
    int nb = (n + 511) >> 9;
    uint v = (t < nb) ? btot[t] : 0;
    s[t] = v;
    __syncthreads();
    for (int off = 1; off < 256; off <<= 1) {
        uint u = (t >= off) ? s[t - off] : 0;
        __syncthreads();
        s[t] += u;
        __syncthreads();
    }
    if (t < nb) bbase[t] = s[t] - v;
    if (t == nb - 1) bbase[nb] = s[t];
    if (t == 0) rp[n] = E;
}

__global__ __launch_bounds__(256) void scat_k(const int* __restrict__ ei,
                                              const uint* __restrict__ bbase,
                                              const uint* __restrict__ histex,
                                              uint* __restrict__ pairs, int E, int n) {
    __shared__ uint cur[256];
    int t = threadIdx.x, blk = blockIdx.x;
    int nb = (n + 511) >> 9;
    if (t < nb) cur[t] = bbase[t] + histex[(size_t)t * 256 + blk];
    __syncthreads();
    int chunk = (E + 255) / 256;
    int e0 = blk * chunk, e1 = min(E, e0 + chunk);
    for (int e = e0 + t; e < e1; e += 256) {
        uint src = (uint)ei[e];
        uint dst = (uint)ei[(size_t)E + e];
        uint p = atomicAdd(&cur[dst >> 9], 1u);
        pairs[p] = (src << 9) | (dst & 511u);
    }
}

__global__ __launch_bounds__(256) void build_k(const uint* __restrict__ pairs,
                                               const uint* __restrict__ bbase,
                                               int* __restrict__ rp,
                                               float* __restrict__ dinv,
                                               int* __restrict__ eb, int n) {
    __shared__ uint lcnt[512];
    __shared__ uint lsc[256];
    int t = threadIdx.x, b = blockIdx.x;
    uint e0 = bbase[b], e1 = bbase[b + 1];
    lcnt[t] = 0;
    lcnt[t + 256] = 0;
    __syncthreads();
    for (uint e = e0 + t; e < e1; e += 256)
        atomicAdd(&lcnt[pairs[e] & 511u], 1u);
    __syncthreads();
    uint c0 = lcnt[2 * t], c1 = lcnt[2 * t + 1];
    uint sm = c0 + c1;
    lsc[t] = sm;
    __syncthreads();
    for (int off = 1; off < 256; off <<= 1) {
        uint u = (t >= off) ? lsc[t - off] : 0;
        __syncthreads();
        lsc[t] += u;
        __syncthreads();
    }
    uint ex = lsc[t] - sm;
    int node0 = (b << 9) + 2 * t;
    if (node0 < n) {
        rp[node0] = (int)(e0 + ex);
        dinv[node0] = rsqrtf((float)(c0 + 1));
    }
    if (node0 + 1 < n) {
        rp[node0 + 1] = (int)(e0 + ex + c0);
        dinv[node0 + 1] = rsqrtf((float)(c1 + 1));
    }
    lcnt[2 * t] = e0 + ex;
    lcnt[2 * t + 1] = e0 + ex + c0;
    __syncthreads();
    for (uint e = e0 + t; e < e1; e += 256) {
        uint p = pairs[e];
        uint pos = atomicAdd(&lcnt[p & 511u], 1u);
        eb[pos] = (int)(p >> 9);
    }
}

// ================= MFMA bf16 GEMM (unchanged) =================

template <int OUTC, bool INB>
__global__ __launch_bounds__(256) void mgemm_k(const void* __restrict__ Xv,
                                               const float* __restrict__ W,
                                               const float* __restrict__ dinv,
                                               uint* __restrict__ outb, int n) {
    constexpr int WOFF = 32768;
    constexpr int C4 = OUTC / 4;
    constexpr int NC = OUTC / 16;
    constexpr int LDSB = (32768 + OUTC * 256) > (128 * OUTC * 4)
                             ? (32768 + OUTC * 256) : (128 * OUTC * 4);
    __shared__ uint4 ldsv[LDSB / 16];
    char* lds = (char*)ldsv;

    int t = threadIdx.x;
    int r0b = blockIdx.x * 128;

    for (int i = t; i < 128 * C4; i += 256) {
        int k = i / C4, c0 = (i % C4) * 4;
        float4 w = ((const float4*)W)[i];
        const float* wf = (const float*)&w;
#pragma unroll
        for (int j = 0; j < 4; ++j) {
            int c = c0 + j;
            *(ushort*)(lds + WOFF + c * 256 + ((k * 2) ^ ((c & 7) << 4))) = f2bu(wf[j]);
        }
    }
    if constexpr (!INB) {
        for (int i = t; i < 128 * 32; i += 256) {
            int r = i >> 5, kq = i & 31;
            uint2 p = make_uint2(0u, 0u);
            if (r0b + r < n) {
                float4 v = ((const float4*)Xv)[(size_t)(r0b + r) * 32 + kq];
                p = make_uint2(fpack2(v.x, v.y), fpack2(v.z, v.w));
            }
            *(uint2*)(lds + r * 256 + ((kq * 8) ^ ((r & 7) << 4))) = p;
        }
    } else {
        for (int i = t; i < 128 * 16; i += 256) {
            int r = i >> 4, kq = i & 15;
            uint4 p = make_uint4(0u, 0u, 0u, 0u);
            if (r0b + r < n) p = ((const uint4*)Xv)[(size_t)(r0b + r) * 16 + kq];
            *(uint4*)(lds + r * 256 + ((kq * 16) ^ ((r & 7) << 4))) = p;
        }
    }
    __syncthreads();

    int wv = t >> 6, lane = t & 63;
    int l15 = lane & 15, lg = lane >> 4;
    int wr0 = wv * 32;
    int swz = (l15 & 7) << 4;

    f32x4 acc[2][NC];
#pragma unroll
    for (int r = 0; r < 2; ++r)
#pragma unroll
        for (int cj = 0; cj < NC; ++cj) acc[r][cj] = (f32x4){0.f, 0.f, 0.f, 0.f};

#pragma unroll
    for (int kk = 0; kk < 4; ++kk) {
        int koff = kk * 64 + lg * 16;
        bf16x8 a0 = *(bf16x8*)(lds + (wr0 + l15) * 256 + (koff ^ swz));
        bf16x8 a1 = *(bf16x8*)(lds + (wr0 + 16 + l15) * 256 + (koff ^ swz));
#pragma unroll
        for (int cj = 0; cj < NC; ++cj) {
            int c = cj * 16 + l15;
            bf16x8 bv = *(bf16x8*)(lds + WOFF + c * 256 + (koff ^ swz));
            acc[0][cj] = __builtin_amdgcn_mfma_f32_16x16x32_bf16(a0, bv, acc[0][cj], 0, 0, 0);
            acc[1][cj] = __builtin_amdgcn_mfma_f32_16x16x32_bf16(a1, bv, acc[1][cj], 0, 0, 0);
        }
    }
    __syncthreads();

#pragma unroll
    for (int r = 0; r < 2; ++r)
#pragma unroll
        for (int cj = 0; cj < NC; ++cj) {
            int row = wr0 + r * 16 + lg * 4;
            int col = cj * 16 + l15;
#pragma unroll
            for (int j = 0; j < 4; ++j)
                *(float*)(lds + ((size_t)(row + j) * OUTC + col) * 4) = acc[r][cj][j];
        }
    __syncthreads();

    for (int i = t; i < 128 * C4; i += 256) {
        int r = i / C4, c4 = (i % C4) * 4;
        if (r0b + r < n) {
            float di = dinv[r0b + r];
            float4 d = *(float4*)(lds + (size_t)i * 16);
            uint2 p = make_uint2(fpack2(d.x * di, d.y * di), fpack2(d.z * di, d.w * di));
            *(uint2*)&outb[(size_t)(r0b + r) * (OUTC / 2) + (c4 >> 1)] = p;
        }
    }
}

// ================= Aggregation v3: XCD-sharded channel groups =================
// Channel group g = blockIdx.x & 7 rides the round-robin block->XCD mapping, so
// each XCD's L2 only caches a 1/8 channel slice of hs (3.2 MB / 1.6 MB < 4 MB).
// agg128: group = 16 ch; lane = (edge_slot 0..15) x (ch_quad 0..3).
// Reduce over edge slots via shfl_xor strides 4,8,16,32.

template <int DPB>
__global__ __launch_bounds__(256) void agg128g_k(const uint2* __restrict__ hs,
                                                 const int* __restrict__ rp,
                                                 const int* __restrict__ eb,
                                                 const float* __restrict__ dinv,
                                                 const float4* __restrict__ bias,
                                                 uint2* __restrict__ outb, int n) {
    int g = blockIdx.x & 7;
    int chunk = blockIdx.x >> 3;
    int wave = threadIdx.x >> 6, lane = threadIdx.x & 63;
    int cq = lane & 3;        // channel quad within group (4 ch)
    int slot = lane >> 2;     // edge slot 0..15
    const uint2* base = hs + g * 4 + cq;   // row stride 32 uint2
    float4 b = bias[g * 4 + cq];

    int d0 = chunk * DPB;
    int dend = min(n, d0 + DPB);
    for (int d = d0 + wave; d < dend; d += 4) {
        int e0 = rp[d], e1 = rp[d + 1];
        float a0 = 0.f, a1 = 0.f, a2 = 0.f, a3 = 0.f;
        for (int e = e0; e < e1; e += 16) {
            int idx = e + slot;
            uint2 v = make_uint2(0u, 0u);
            if (idx < e1) v = base[(size_t)eb[idx] << 5];
            a0 += blo(v.x); a1 += bhi(v.x); a2 += blo(v.y); a3 += bhi(v.y);
        }
#pragma unroll
        for (int m = 4; m < 64; m <<= 1) {
            a0 += __shfl_xor(a0, m, 64);
            a1 += __shfl_xor(a1, m, 64);
            a2 += __shfl_xor(a2, m, 64);
            a3 += __shfl_xor(a3, m, 64);
        }
        if (slot == 0) {
            uint2 s = base[(size_t)d << 5];
            a0 += blo(s.x); a1 += bhi(s.x); a2 += blo(s.y); a3 += bhi(s.y);
            float di = dinv[d];
            uint2 p = make_uint2(
                fpack2(fmaxf(a0 * di + b.x, 0.f), fmaxf(a1 * di + b.y, 0.f)),
                fpack2(fmaxf(a2 * di + b.z, 0.f), fmaxf(a3 * di + b.w, 0.f)));
            outb[((size_t)d << 5) + g * 4 + cq] = p;
        }
    }
}

// agg64: group = 8 ch; lane = (edge_slot 0..31) x (ch_quad 0..1).
// Reduce strides 2,4,8,16,32. Output f32.

template <int DPB>
__global__ __launch_bounds__(256) void agg64g_k(const uint2* __restrict__ hs,
                                                const int* __restrict__ rp,
                                                const int* __restrict__ eb,
                                                const float* __restrict__ dinv,
                                                const float4* __restrict__ bias,
                                                float4* __restrict__ out, int n) {
    int g = blockIdx.x & 7;
    int chunk = blockIdx.x >> 3;
    int wave = threadIdx.x >> 6, lane = threadIdx.x & 63;
    int cq = lane & 1;        // channel quad within group
    int slot = lane >> 1;     // edge slot 0..31
    const uint2* base = hs + g * 2 + cq;   // row stride 16 uint2
    float4 b = bias[g * 2 + cq];

    int d0 = chunk * DPB;
    int dend = min(n, d0 + DPB);
    for (int d = d0 + wave; d < dend; d += 4) {
        int e0 = rp[d], e1 = rp[d + 1];
        float a0 = 0.f, a1 = 0.f, a2 = 0.f, a3 = 0.f;
        for (int e = e0; e < e1; e += 32) {
            int idx = e + slot;
            uint2 v = make_uint2(0u, 0u);
            if (idx < e1) v = base[(size_t)eb[idx] << 4];
            a0 += blo(v.x); a1 += bhi(v.x); a2 += blo(v.y); a3 += bhi(v.y);
        }
#pragma unroll
        for (int m = 2; m < 64; m <<= 1) {
            a0 += __shfl_xor(a0, m, 64);
            a1 += __shfl_xor(a1, m, 64);
            a2 += __shfl_xor(a2, m, 64);
            a3 += __shfl_xor(a3, m, 64);
        }
        if (slot == 0) {
            uint2 s = base[(size_t)d << 4];
            a0 += blo(s.x); a1 += bhi(s.x); a2 += blo(s.y); a3 += bhi(s.y);
            float di = dinv[d];
            out[((size_t)d << 4) + g * 2 + cq] =
                make_float4(a0 * di + b.x, a1 * di + b.y, a2 * di + b.z, a3 * di + b.w);
        }
    }
}

// ================= launch =================

extern "C" void kernel_launch(void* const* d_in, const int* in_sizes, int n_in,
                              void* d_out, int out_size, void* d_ws, size_t ws_size,
                              hipStream_t stream) {
    const float* x  = (const float*)d_in[0];
    const int*   ei = (const int*)d_in[1];
    const float* W1 = (const float*)d_in[2];
    const float* b1 = (const float*)d_in[3];
    const float* W2 = (const float*)d_in[4];
    const float* b2 = (const float*)d_in[5];
    float* out = (float*)d_out;

    int n = in_sizes[0] / 128;
    int E = in_sizes[1] / 2;
    int nb = (n + 511) >> 9;

    char* ws = (char*)d_ws;
    size_t o = 0;
    auto alloc = [&](size_t bytes) {
        size_t r = o;
        o = (o + bytes + 255) & ~(size_t)255;
        return r;
    };
    uint*  hist   = (uint*)(ws + alloc((size_t)256 * 256 * 4));
    uint*  histex = (uint*)(ws + alloc((size_t)256 * 256 * 4));
    uint*  btot   = (uint*)(ws + alloc(256 * 4));
    uint*  bbase  = (uint*)(ws + alloc(257 * 4));
    int*   rp     = (int*)(ws + alloc((size_t)(n + 1) * 4));
    float* dinv   = (float*)(ws + alloc((size_t)n * 4));
    uint*  pairs  = (uint*)(ws + alloc((size_t)E * 4));
    int*   eb     = (int*)(ws + alloc((size_t)E * 4));
    uint*  h1s    = (uint*)(ws + alloc((size_t)n * 64 * 4));
    uint*  a1     = (uint*)(ws + alloc((size_t)n * 64 * 4));
    uint*  h2s    = (uint*)(ws + alloc((size_t)n * 32 * 4));

    int gB = (n + 127) / 128;
    constexpr int DPB = 64;
    int gG = 8 * ((n + DPB - 1) / DPB);

    hist_k<<<256, 256, 0, stream>>>(ei, hist, E, n);
    scanA_k<<<nb, 256, 0, stream>>>(hist, histex, btot);
    scanB_k<<<1, 256, 0, stream>>>(btot, bbase, rp, n, E);
    scat_k<<<256, 256, 0, stream>>>(ei, bbase, histex, pairs, E, n);
    build_k<<<nb, 256, 0, stream>>>(pairs, bbase, rp, dinv, eb, n);

    mgemm_k<128, false><<<gB, 256, 0, stream>>>(x, W1, dinv, h1s, n);
    agg128g_k<DPB><<<gG, 256, 0, stream>>>((const uint2*)h1s, rp, eb, dinv,
                                           (const float4*)b1, (uint2*)a1, n);
    mgemm_k<64, true><<<gB, 256, 0, stream>>>(a1, W2, dinv, h2s, n);
    agg64g_k<DPB><<<gG, 256, 0, stream>>>((const uint2*)h2s, rp, eb, dinv,
                                          (const float4*)b2, (float4*)out, n);
}

// Round 7
// 218.658 us; speedup vs baseline: 2.5529x; 2.5529x over previous
//
#include <hip/hip_runtime.h>
#include <hip/hip_bf16.h>
#include <cstdint>

typedef short bf16x8 __attribute__((ext_vector_type(8)));
typedef float f32x4 __attribute__((ext_vector_type(4)));

// ---------------- bf16 helpers ----------------

__device__ inline float blo(uint u) { return __uint_as_float(u << 16); }
__device__ inline float bhi(uint u) { return __uint_as_float(u & 0xffff0000u); }
__device__ inline ushort f2bu(float x) {
    __hip_bfloat16 h = __float2bfloat16(x);
    return *reinterpret_cast<ushort*>(&h);
}
__device__ inline uint fpack2(float x, float y) {
    return (uint)f2bu(x) | ((uint)f2bu(y) << 16);
}

// ================= bucketed CSR build =================

__global__ __launch_bounds__(256) void hist_k(const int* __restrict__ ei,
                                              uint* __restrict__ hist, int E, int n) {
    __shared__ uint h[256];
    int t = threadIdx.x, blk = blockIdx.x;
    int nb = (n + 511) >> 9;
    h[t] = 0;
    __syncthreads();
    int chunk = (E + 255) / 256;
    int e0 = blk * chunk, e1 = min(E, e0 + chunk);
    for (int e = e0 + t; e < e1; e += 256)
        atomicAdd(&h[((uint)ei[(size_t)E + e]) >> 9], 1u);
    __syncthreads();
    if (t < nb) hist[(size_t)t * 256 + blk] = h[t];
}

__global__ __launch_bounds__(256) void scanA_k(const uint* __restrict__ hist,
                                               uint* __restrict__ histex,
                                               uint* __restrict__ btot) {
    __shared__ uint s[256];
    int t = threadIdx.x, b = blockIdx.x;
    uint v = hist[(size_t)b * 256 + t];
    s[t] = v;
    __syncthreads();
    for (int off = 1; off < 256; off <<= 1) {
        uint u = (t >= off) ? s[t - off] : 0;
        __syncthreads();
        s[t] += u;
        __syncthreads();
    }
    histex[(size_t)b * 256 + t] = s[t] - v;
    if (t == 255) btot[b] = s[255];
}

__global__ __launch_bounds__(256) void scanB_k(const uint* __restrict__ btot,
                                               uint* __restrict__ bbase,
                                               int* __restrict__ rp, int n, int E) {
    __shared__ uint s[256];
    int t = threadIdx.x;
    int nb = (n + 511) >> 9;
    uint v = (t < nb) ? btot[t] : 0;
    s[t] = v;
    __syncthreads();
    for (int off = 1; off < 256; off <<= 1) {
        uint u = (t >= off) ? s[t - off] : 0;
        __syncthreads();
        s[t] += u;
        __syncthreads();
    }
    if (t < nb) bbase[t] = s[t] - v;
    if (t == nb - 1) bbase[nb] = s[t];
    if (t == 0) rp[n] = E;
}

__global__ __launch_bounds__(256) void scat_k(const int* __restrict__ ei,
                                              const uint* __restrict__ bbase,
                                              const uint* __restrict__ histex,
                                              uint* __restrict__ pairs, int E, int n) {
    __shared__ uint cur[256];
    int t = threadIdx.x, blk = blockIdx.x;
    int nb = (n + 511) >> 9;
    if (t < nb) cur[t] = bbase[t] + histex[(size_t)t * 256 + blk];
    __syncthreads();
    int chunk = (E + 255) / 256;
    int e0 = blk * chunk, e1 = min(E, e0 + chunk);
    for (int e = e0 + t; e < e1; e += 256) {
        uint src = (uint)ei[e];
        uint dst = (uint)ei[(size_t)E + e];
        uint p = atomicAdd(&cur[dst >> 9], 1u);
        pairs[p] = (src << 9) | (dst & 511u);
    }
}

__global__ __launch_bounds__(256) void build_k(const uint* __restrict__ pairs,
                                               const uint* __restrict__ bbase,
                                               int* __restrict__ rp,
                                               float* __restrict__ dinv,
                                               int* __restrict__ eb, int n) {
    __shared__ uint lcnt[512];
    __shared__ uint lsc[256];
    int t = threadIdx.x, b = blockIdx.x;
    uint e0 = bbase[b], e1 = bbase[b + 1];
    lcnt[t] = 0;
    lcnt[t + 256] = 0;
    __syncthreads();
    for (uint e = e0 + t; e < e1; e += 256)
        atomicAdd(&lcnt[pairs[e] & 511u], 1u);
    __syncthreads();
    uint c0 = lcnt[2 * t], c1 = lcnt[2 * t + 1];
    uint sm = c0 + c1;
    lsc[t] = sm;
    __syncthreads();
    for (int off = 1; off < 256; off <<= 1) {
        uint u = (t >= off) ? lsc[t - off] : 0;
        __syncthreads();
        lsc[t] += u;
        __syncthreads();
    }
    uint ex = lsc[t] - sm;
    int node0 = (b << 9) + 2 * t;
    if (node0 < n) {
        rp[node0] = (int)(e0 + ex);
        dinv[node0] = rsqrtf((float)(c0 + 1));
    }
    if (node0 + 1 < n) {
        rp[node0 + 1] = (int)(e0 + ex + c0);
        dinv[node0 + 1] = rsqrtf((float)(c1 + 1));
    }
    lcnt[2 * t] = e0 + ex;
    lcnt[2 * t + 1] = e0 + ex + c0;
    __syncthreads();
    for (uint e = e0 + t; e < e1; e += 256) {
        uint p = pairs[e];
        uint pos = atomicAdd(&lcnt[p & 511u], 1u);
        eb[pos] = (int)(p >> 9);
    }
}

// ================= W pre-convert: f32 [128][OUTC] -> bf16 swizzled image =================
// Wb[c*128 + (k ^ ((c&7)<<3))] = bf16(W[k][c]); matches mgemm's LDS W layout.

__global__ __launch_bounds__(256) void wprep_k(const float* __restrict__ W,
                                               ushort* __restrict__ Wb, int OUTC) {
    int idx = blockIdx.x * 256 + threadIdx.x;
    if (idx >= OUTC * 128) return;
    int k = idx / OUTC, c = idx % OUTC;          // coalesced read of W
    Wb[c * 128 + (k ^ ((c & 7) << 3))] = f2bu(W[idx]);
}

// ================= MFMA bf16 GEMM =================
// !INB: out[r] = bf16( ((X[r]*dinv[r]) @ W) )   (dinv folded into A-stage)
//  INB: out[r] = bf16( X[r] @ W )               (input rows already carry dinv)

template <int OUTC, bool INB>
__global__ __launch_bounds__(256) void mgemm_k(const void* __restrict__ Xv,
                                               const uint4* __restrict__ Wbv,
                                               const float* __restrict__ dinv,
                                               uint* __restrict__ outb, int n) {
    constexpr int WOFF = 32768;
    constexpr int C4 = OUTC / 4;
    constexpr int NC = OUTC / 16;
    constexpr int LDSB = (32768 + OUTC * 256) > (128 * OUTC * 4)
                             ? (32768 + OUTC * 256) : (128 * OUTC * 4);
    __shared__ uint4 ldsv[LDSB / 16];
    char* lds = (char*)ldsv;

    int t = threadIdx.x;
    int r0b = blockIdx.x * 128;

    // stage W image: straight uint4 copy (pre-swizzled by wprep_k)
    for (int i = t; i < OUTC * 16; i += 256)
        ((uint4*)(lds + WOFF))[i] = Wbv[i];

    if constexpr (!INB) {
        for (int i = t; i < 128 * 32; i += 256) {
            int r = i >> 5, kq = i & 31;
            uint2 p = make_uint2(0u, 0u);
            if (r0b + r < n) {
                float di = dinv[r0b + r];
                float4 v = ((const float4*)Xv)[(size_t)(r0b + r) * 32 + kq];
                p = make_uint2(fpack2(v.x * di, v.y * di), fpack2(v.z * di, v.w * di));
            }
            *(uint2*)(lds + r * 256 + ((kq * 8) ^ ((r & 7) << 4))) = p;
        }
    } else {
        for (int i = t; i < 128 * 16; i += 256) {
            int r = i >> 4, kq = i & 15;
            uint4 p = make_uint4(0u, 0u, 0u, 0u);
            if (r0b + r < n) p = ((const uint4*)Xv)[(size_t)(r0b + r) * 16 + kq];
            *(uint4*)(lds + r * 256 + ((kq * 16) ^ ((r & 7) << 4))) = p;
        }
    }
    __syncthreads();

    int wv = t >> 6, lane = t & 63;
    int l15 = lane & 15, lg = lane >> 4;
    int wr0 = wv * 32;
    int swz = (l15 & 7) << 4;

    f32x4 acc[2][NC];
#pragma unroll
    for (int r = 0; r < 2; ++r)
#pragma unroll
        for (int cj = 0; cj < NC; ++cj) acc[r][cj] = (f32x4){0.f, 0.f, 0.f, 0.f};

#pragma unroll
    for (int kk = 0; kk < 4; ++kk) {
        int koff = kk * 64 + lg * 16;
        bf16x8 a0 = *(bf16x8*)(lds + (wr0 + l15) * 256 + (koff ^ swz));
        bf16x8 a1 = *(bf16x8*)(lds + (wr0 + 16 + l15) * 256 + (koff ^ swz));
#pragma unroll
        for (int cj = 0; cj < NC; ++cj) {
            int c = cj * 16 + l15;
            bf16x8 bv = *(bf16x8*)(lds + WOFF + c * 256 + (koff ^ swz));
            acc[0][cj] = __builtin_amdgcn_mfma_f32_16x16x32_bf16(a0, bv, acc[0][cj], 0, 0, 0);
            acc[1][cj] = __builtin_amdgcn_mfma_f32_16x16x32_bf16(a1, bv, acc[1][cj], 0, 0, 0);
        }
    }
    __syncthreads();

    // D -> LDS f32 [128][OUTC]  (C/D layout: col = lane&15, row = (lane>>4)*4 + reg)
#pragma unroll
    for (int r = 0; r < 2; ++r)
#pragma unroll
        for (int cj = 0; cj < NC; ++cj) {
            int row = wr0 + r * 16 + lg * 4;
            int col = cj * 16 + l15;
#pragma unroll
            for (int j = 0; j < 4; ++j)
                *(float*)(lds + ((size_t)(row + j) * OUTC + col) * 4) = acc[r][cj][j];
        }
    __syncthreads();

    for (int i = t; i < 128 * C4; i += 256) {
        int r = i / C4, c4 = (i % C4) * 4;
        if (r0b + r < n) {
            float4 d = *(float4*)(lds + (size_t)i * 16);
            uint2 p = make_uint2(fpack2(d.x, d.y), fpack2(d.z, d.w));
            *(uint2*)&outb[(size_t)(r0b + r) * (OUTC / 2) + (c4 >> 1)] = p;
        }
    }
}

// ================= Aggregation (round-4 proven versions) =================
// agg128: one wave/node, lane covers 4 ch (uint2), halves handle alternating edges.
// Output a1 is pre-scaled by dinv[wid] (folds layer-2 GEMM's row scale).

__global__ __launch_bounds__(256) void agg128_k(const uint2* __restrict__ hs,
                                                const int* __restrict__ rp,
                                                const int* __restrict__ eb,
                                                const float* __restrict__ dinv,
                                                const float4* __restrict__ bias,
                                                uint2* __restrict__ outb, int n) {
    int wid = (blockIdx.x * 256 + threadIdx.x) >> 6;
    int lane = threadIdx.x & 63;
    if (wid >= n) return;
    int h = lane >> 5;
    int cq = lane & 31;
    int e0 = rp[wid], e1 = rp[wid + 1];
    const uint2* base = hs + cq;

    float a0 = 0.f, a1 = 0.f, a2 = 0.f, a3 = 0.f;
    if (h == 0) {
        uint2 s = base[(size_t)wid << 5];
        a0 = blo(s.x); a1 = bhi(s.x); a2 = blo(s.y); a3 = bhi(s.y);
    }

    int e = e0;
    for (; e + 16 <= e1; e += 16) {
        int s0 = eb[e + 0 + h], s1 = eb[e + 2 + h], s2 = eb[e + 4 + h], s3 = eb[e + 6 + h];
        int s4 = eb[e + 8 + h], s5 = eb[e + 10 + h], s6 = eb[e + 12 + h], s7 = eb[e + 14 + h];
        uint2 v0 = base[(size_t)s0 << 5];
        uint2 v1 = base[(size_t)s1 << 5];
        uint2 v2 = base[(size_t)s2 << 5];
        uint2 v3 = base[(size_t)s3 << 5];
        uint2 v4 = base[(size_t)s4 << 5];
        uint2 v5 = base[(size_t)s5 << 5];
        uint2 v6 = base[(size_t)s6 << 5];
        uint2 v7 = base[(size_t)s7 << 5];
        a0 += ((blo(v0.x) + blo(v1.x)) + (blo(v2.x) + blo(v3.x))) +
              ((blo(v4.x) + blo(v5.x)) + (blo(v6.x) + blo(v7.x)));
        a1 += ((bhi(v0.x) + bhi(v1.x)) + (bhi(v2.x) + bhi(v3.x))) +
              ((bhi(v4.x) + bhi(v5.x)) + (bhi(v6.x) + bhi(v7.x)));
        a2 += ((blo(v0.y) + blo(v1.y)) + (blo(v2.y) + blo(v3.y))) +
              ((blo(v4.y) + blo(v5.y)) + (blo(v6.y) + blo(v7.y)));
        a3 += ((bhi(v0.y) + bhi(v1.y)) + (bhi(v2.y) + bhi(v3.y))) +
              ((bhi(v4.y) + bhi(v5.y)) + (bhi(v6.y) + bhi(v7.y)));
    }
    for (; e + 2 <= e1; e += 2) {
        int s = eb[e + h];
        uint2 v = base[(size_t)s << 5];
        a0 += blo(v.x); a1 += bhi(v.x); a2 += blo(v.y); a3 += bhi(v.y);
    }
    if (e < e1 && h == 0) {
        uint2 v = base[(size_t)eb[e] << 5];
        a0 += blo(v.x); a1 += bhi(v.x); a2 += blo(v.y); a3 += bhi(v.y);
    }

    a0 += __shfl_xor(a0, 32, 64);
    a1 += __shfl_xor(a1, 32, 64);
    a2 += __shfl_xor(a2, 32, 64);
    a3 += __shfl_xor(a3, 32, 64);

    if (h == 0) {
        float di = dinv[wid];
        float4 b = bias[cq];
        // relu(acc*di + b) * di  — trailing *di folds the layer-2 row scale
        uint2 p = make_uint2(
            fpack2(fmaxf(a0 * di + b.x, 0.f) * di, fmaxf(a1 * di + b.y, 0.f) * di),
            fpack2(fmaxf(a2 * di + b.z, 0.f) * di, fmaxf(a3 * di + b.w, 0.f) * di));
        outb[((size_t)wid << 5) + cq] = p;
    }
}

__global__ __launch_bounds__(256) void agg64_k(const uint2* __restrict__ hs,
                                               const int* __restrict__ rp,
                                               const int* __restrict__ eb,
                                               const float* __restrict__ dinv,
                                               const float4* __restrict__ bias,
                                               float4* __restrict__ out, int n) {
    int wid = (blockIdx.x * 256 + threadIdx.x) >> 6;
    int lane = threadIdx.x & 63;
    if (wid >= n) return;
    int h = lane >> 4;
    int cq = lane & 15;
    int e0 = rp[wid], e1 = rp[wid + 1];
    const uint2* base = hs + cq;

    float a0 = 0.f, a1 = 0.f, a2 = 0.f, a3 = 0.f;
    if (h == 0) {
        uint2 s = base[(size_t)wid << 4];
        a0 = blo(s.x); a1 = bhi(s.x); a2 = blo(s.y); a3 = bhi(s.y);
    }

    int e = e0;
    for (; e + 16 <= e1; e += 16) {
        int s0 = eb[e + 0 + h], s1 = eb[e + 4 + h], s2 = eb[e + 8 + h], s3 = eb[e + 12 + h];
        uint2 v0 = base[(size_t)s0 << 4];
        uint2 v1 = base[(size_t)s1 << 4];
        uint2 v2 = base[(size_t)s2 << 4];
        uint2 v3 = base[(size_t)s3 << 4];
        a0 += (blo(v0.x) + blo(v1.x)) + (blo(v2.x) + blo(v3.x));
        a1 += (bhi(v0.x) + bhi(v1.x)) + (bhi(v2.x) + bhi(v3.x));
        a2 += (blo(v0.y) + blo(v1.y)) + (blo(v2.y) + blo(v3.y));
        a3 += (bhi(v0.y) + bhi(v1.y)) + (bhi(v2.y) + bhi(v3.y));
    }
    for (; e + 4 <= e1; e += 4) {
        int s = eb[e + h];
        uint2 v = base[(size_t)s << 4];
        a0 += blo(v.x); a1 += bhi(v.x); a2 += blo(v.y); a3 += bhi(v.y);
    }
    if (e + h < e1) {
        uint2 v = base[(size_t)eb[e + h] << 4];
        a0 += blo(v.x); a1 += bhi(v.x); a2 += blo(v.y); a3 += bhi(v.y);
    }

    a0 += __shfl_xor(a0, 16, 64);
    a1 += __shfl_xor(a1, 16, 64);
    a2 += __shfl_xor(a2, 16, 64);
    a3 += __shfl_xor(a3, 16, 64);
    a0 += __shfl_xor(a0, 32, 64);
    a1 += __shfl_xor(a1, 32, 64);
    a2 += __shfl_xor(a2, 32, 64);
    a3 += __shfl_xor(a3, 32, 64);

    if (h == 0) {
        float di = dinv[wid];
        float4 b = bias[cq];
        out[((size_t)wid << 4) + cq] =
            make_float4(a0 * di + b.x, a1 * di + b.y, a2 * di + b.z, a3 * di + b.w);
    }
}

// ================= launch =================

extern "C" void kernel_launch(void* const* d_in, const int* in_sizes, int n_in,
                              void* d_out, int out_size, void* d_ws, size_t ws_size,
                              hipStream_t stream) {
    const float* x  = (const float*)d_in[0];
    const int*   ei = (const int*)d_in[1];
    const float* W1 = (const float*)d_in[2];
    const float* b1 = (const float*)d_in[3];
    const float* W2 = (const float*)d_in[4];
    const float* b2 = (const float*)d_in[5];
    float* out = (float*)d_out;

    int n = in_sizes[0] / 128;
    int E = in_sizes[1] / 2;
    int nb = (n + 511) >> 9;

    char* ws = (char*)d_ws;
    size_t o = 0;
    auto alloc = [&](size_t bytes) {
        size_t r = o;
        o = (o + bytes + 255) & ~(size_t)255;
        return r;
    };
    uint*   hist   = (uint*)(ws + alloc((size_t)256 * 256 * 4));
    uint*   histex = (uint*)(ws + alloc((size_t)256 * 256 * 4));
    uint*   btot   = (uint*)(ws + alloc(256 * 4));
    uint*   bbase  = (uint*)(ws + alloc(257 * 4));
    int*    rp     = (int*)(ws + alloc((size_t)(n + 1) * 4));
    float*  dinv   = (float*)(ws + alloc((size_t)n * 4));
    uint*   pairs  = (uint*)(ws + alloc((size_t)E * 4));
    int*    eb     = (int*)(ws + alloc((size_t)E * 4));
    ushort* W1b    = (ushort*)(ws + alloc((size_t)128 * 128 * 2));
    ushort* W2b    = (ushort*)(ws + alloc((size_t)64 * 128 * 2));
    uint*   h1s    = (uint*)(ws + alloc((size_t)n * 64 * 4));
    uint*   a1     = (uint*)(ws + alloc((size_t)n * 64 * 4));
    uint*   h2s    = (uint*)(ws + alloc((size_t)n * 32 * 4));

    int gB = (n + 127) / 128;
    int gW = (int)(((size_t)n * 64 + 255) / 256);

    hist_k<<<256, 256, 0, stream>>>(ei, hist, E, n);
    scanA_k<<<nb, 256, 0, stream>>>(hist, histex, btot);
    scanB_k<<<1, 256, 0, stream>>>(btot, bbase, rp, n, E);
    scat_k<<<256, 256, 0, stream>>>(ei, bbase, histex, pairs, E, n);
    build_k<<<nb, 256, 0, stream>>>(pairs, bbase, rp, dinv, eb, n);
    wprep_k<<<(128 * 128 + 255) / 256, 256, 0, stream>>>(W1, W1b, 128);
    wprep_k<<<(64 * 128 + 255) / 256, 256, 0, stream>>>(W2, W2b, 64);

    // layer 1: h1s = bf16((x*dinv)@W1) ; a1 = bf16(relu(agg(h1s)*dinv + b1) * dinv)
    mgemm_k<128, false><<<gB, 256, 0, stream>>>(x, (const uint4*)W1b, dinv, h1s, n);
    agg128_k<<<gW, 256, 0, stream>>>((const uint2*)h1s, rp, eb, dinv,
                                     (const float4*)b1, (uint2*)a1, n);
    // layer 2: h2s = bf16(a1@W2) (dinv already folded) ; out = agg(h2s)*dinv + b2
    mgemm_k<64, true><<<gB, 256, 0, stream>>>(a1, (const uint4*)W2b, dinv, h2s, n);
    agg64_k<<<gW, 256, 0, stream>>>((const uint2*)h2s, rp, eb, dinv,
                                    (const float4*)b2, (float4*)out, n);
}